// Round 11
// baseline (343.321 us; speedup 1.0000x reference)
//
#include <hip/hip_runtime.h>
#include <math.h>

// ---------------------------------------------------------------------------
// GCN fraud-model forward:
//   out = A(relu(A(x*sig(mask) @ W1) + b1) @ (W2@Wc)) + (b2@Wc + bc)
// A-linearity folds W2@Wc -> [128,2].
//
// R3: dinv folded into stored rows; H1n packed bf16 (256B/row).
// R4: gemm1 -> MFMA bf16 32x32x16, XOR-swizzled LDS.
// R6: line-local CSR build (bin partition + per-bin block).
// R8: packed edges (src|ld<<20), scalarized agg index streams. [171us]
// R9: coop grid.sync REGRESSED 2.6x (cross-XCD L2 drains). Reverted.
// R10: agg1 2-nodes/wave REGRESSED (59.6->71.6us: halved TLP). Reverted.
// R11: hist+scan ELIMINATED: csr/psd get fixed-capacity padded bin regions
//      (offsets/counts are the only interface agg uses -- csr need not be
//      dense). partP = one pass, global atomic sub-cursors
//      cursor[bin*8+blk&7] (2048 spread counters, same-XCD sub-runs keep
//      line fill L2-local). Saves dst pre-read + scanP + 2 launches.
// ---------------------------------------------------------------------------

constexpr int NBIN = 256;    // partition bins (~391 nodes each)
constexpr int PNB = 256;     // partition blocks
constexpr int CAPB = 9600;   // per-bin edge capacity (mean 6250, +42 sigma)
constexpr int SUBCAP = CAPB / 8;

typedef __attribute__((ext_vector_type(8))) short bf16x8;
typedef __attribute__((ext_vector_type(16))) float f32x16;

__device__ __forceinline__ unsigned bf16rtn(float f) {
  unsigned b = __float_as_uint(f);
  b += 0x7FFFu + ((b >> 16) & 1u);   // round-to-nearest-even
  return b >> 16;
}
__device__ __forceinline__ float2 bf2unpack(unsigned u) {
  float2 r;
  r.x = __uint_as_float(u << 16);
  r.y = __uint_as_float(u & 0xFFFF0000u);
  return r;
}

// ---------- prep: scalars (blk 0) + W1^T bf16 (blks 1..32) + zero cursors (33)
__global__ void prep_kernel(const float* __restrict__ fmask, const float* __restrict__ W2,
                            const float* __restrict__ b2, const float* __restrict__ Wc,
                            const float* __restrict__ bc, const float* __restrict__ W1,
                            float* __restrict__ sm, float* __restrict__ Wf,
                            float* __restrict__ bf, unsigned* __restrict__ W1Tg,
                            int* __restrict__ cursor) {
  int t = threadIdx.x;
  int b = blockIdx.x;
  if (b == 0) {
    if (t < 128) {
      sm[t] = 1.0f / (1.0f + expf(-fmask[t]));
      float w0 = 0.f, w1 = 0.f;
      for (int k = 0; k < 128; ++k) {
        float v = W2[t * 128 + k];
        w0 = fmaf(v, Wc[k * 2 + 0], w0);
        w1 = fmaf(v, Wc[k * 2 + 1], w1);
      }
      Wf[t * 2 + 0] = w0;
      Wf[t * 2 + 1] = w1;
    }
    if (t >= 128 && t < 130) {
      int j = t - 128;
      float s = bc[j];
      for (int k = 0; k < 128; ++k) s = fmaf(b2[k], Wc[k * 2 + j], s);
      bf[j] = s;
    }
  } else if (b <= 32) {
    int p = (b - 1) * 256 + t;  // 0..8191
    if (p < 8192) {
      int j = p >> 6;
      int kp = (p & 63) * 2;
      float a = W1[(size_t)kp * 128 + j];
      float bb = W1[(size_t)(kp + 1) * 128 + j];
      W1Tg[p] = bf16rtn(a) | (bf16rtn(bb) << 16);
    }
  } else {
#pragma unroll
    for (int j = 0; j < 8; ++j) cursor[t * 8 + j] = 0;
  }
}

// ---------- single-pass partition: psd[bin region] = src | local_d<<20 ------
__global__ void partP_kernel(const int* __restrict__ src, const int* __restrict__ dst,
                             int* __restrict__ cursor, unsigned* __restrict__ psd,
                             int E, unsigned multN) {
  __shared__ int llo[NBIN];
  int t = threadIdx.x;
  int sub = blockIdx.x & 7;
  unsigned long long denom = (unsigned long long)multN * NBIN;
  for (int i = t; i < NBIN; i += blockDim.x)
    llo[i] = (int)((((unsigned long long)i << 32) + denom - 1) / denom);
  __syncthreads();
  int per = (E + PNB - 1) / PNB;
  int e0 = blockIdx.x * per, e1 = min(E, e0 + per);
  for (int e = e0 + t; e < e1; e += blockDim.x) {
    int d = dst[e];
    int s = src[e];
    int b = __umulhi((unsigned)d * NBIN, multN);
    int p = atomicAdd(&cursor[b * 8 + sub], 1);
    psd[(size_t)b * CAPB + sub * SUBCAP + p] = (unsigned)s | ((unsigned)(d - llo[b]) << 20);
  }
}

// ---------- per-bin CSR build from 8 padded sub-runs ----------
__global__ __launch_bounds__(256) void csrbuild_kernel(
    const unsigned* __restrict__ psd, const int* __restrict__ cursor,
    int* __restrict__ offsets, int* __restrict__ counts, float* __restrict__ dinv,
    int* __restrict__ csr, int n, unsigned multN) {
  __shared__ int ldeg[512];
  __shared__ int lcur[512];
  __shared__ int sh[256];
  __shared__ int slen[8];
  int b = blockIdx.x, t = threadIdx.x;
  unsigned long long denom = (unsigned long long)multN * NBIN;
  int lo = (int)((((unsigned long long)b << 32) + denom - 1) / denom);
  int hi = (int)((((unsigned long long)(b + 1) << 32) + denom - 1) / denom);
  if (hi > n) hi = n;
  if (lo > n) lo = n;
  if (t < 8) slen[t] = cursor[b * 8 + t];
#pragma unroll
  for (int j = 0; j < 2; ++j) ldeg[t * 2 + j] = 0;
  __syncthreads();
  size_t bbase = (size_t)b * CAPB;
#pragma unroll
  for (int s = 0; s < 8; ++s) {
    int len = slen[s];
    size_t sb = bbase + s * SUBCAP;
    for (int e = t; e < len; e += 256) atomicAdd(&ldeg[psd[sb + e] >> 20], 1);
  }
  __syncthreads();
  int c[2], loc = 0;
#pragma unroll
  for (int j = 0; j < 2; ++j) {
    c[j] = ldeg[t * 2 + j];
    loc += c[j];
  }
  sh[t] = loc;
  __syncthreads();
  for (int off = 1; off < 256; off <<= 1) {
    int add = (t >= off) ? sh[t - off] : 0;
    __syncthreads();
    sh[t] += add;
    __syncthreads();
  }
  int run = sh[t] - loc;  // exclusive
#pragma unroll
  for (int j = 0; j < 2; ++j) {
    int idx = t * 2 + j;
    lcur[idx] = run;
    int node = lo + idx;
    if (node < hi) {
      offsets[node] = (int)bbase + run;   // base into PADDED csr
      counts[node] = c[j];
      dinv[node] = rsqrtf((float)(c[j] + 1));
    }
    run += c[j];
  }
  __syncthreads();
#pragma unroll
  for (int s = 0; s < 8; ++s) {
    int len = slen[s];
    size_t sb = bbase + s * SUBCAP;
    for (int e = t; e < len; e += 256) {
      unsigned pd = psd[sb + e];
      int p = atomicAdd(&lcur[pd >> 20], 1);
      csr[bbase + p] = (int)(pd & 0xFFFFFu);
    }
  }
}

// ---------- GEMM1 (MFMA): H1n = dinv[row] * ((x*sm) @ W1) in packed bf16 ----
__global__ __launch_bounds__(256) void gemm1_mfma_kernel(
    const float* __restrict__ x, const unsigned* __restrict__ W1Tg,
    const float* __restrict__ sm, const float* __restrict__ dinv,
    unsigned* __restrict__ H1n, int n) {
  __shared__ short lw1t[16384];  // 32 KB, W1T[j][k] bf16, swizzled
  __shared__ short lA[16384];    // 32 KB, A[r][k] bf16, swizzled
  __shared__ float ldv[128];
  int t = threadIdx.x;
  int rowbase = blockIdx.x * 128;

  if (t < 128) {
    int rg = rowbase + t;
    ldv[t] = (rg < n) ? dinv[rg] : 0.f;
  }
#pragma unroll
  for (int i = 0; i < 8; ++i) {
    int g = t + i * 256;
    int j = g >> 4;
    int c8 = (g & 15) * 8;
    uint4 v = *(const uint4*)(W1Tg + j * 64 + (c8 >> 1));
    int so = (j * 128 + c8) ^ ((j & 7) << 3);
    *(uint4*)(&lw1t[so]) = v;
  }
#pragma unroll
  for (int i = 0; i < 8; ++i) {
    int g = t + i * 256;
    int r = g >> 4;
    int c8 = (g & 15) * 8;
    int rowg = rowbase + r;
    uint4 p = {0, 0, 0, 0};
    if (rowg < n) {
      const float* xp = x + (size_t)rowg * 128 + c8;
      float4 xa = *(const float4*)(xp);
      float4 xb = *(const float4*)(xp + 4);
      float4 sa = *(const float4*)(sm + c8);
      float4 sb = *(const float4*)(sm + c8 + 4);
      p.x = bf16rtn(xa.x * sa.x) | (bf16rtn(xa.y * sa.y) << 16);
      p.y = bf16rtn(xa.z * sa.z) | (bf16rtn(xa.w * sa.w) << 16);
      p.z = bf16rtn(xb.x * sb.x) | (bf16rtn(xb.y * sb.y) << 16);
      p.w = bf16rtn(xb.z * sb.z) | (bf16rtn(xb.w * sb.w) << 16);
    }
    int so = (r * 128 + c8) ^ ((r & 7) << 3);
    *(uint4*)(&lA[so]) = p;
  }
  __syncthreads();

  int l = t & 63;
  int w = t >> 6;
  int wbase = w * 32;
  int lp = l & 31;
  int lhi = l >> 5;

  bf16x8 af[8];
#pragma unroll
  for (int kb = 0; kb < 8; ++kb) {
    int row = wbase + lp;
    int so = (row * 128 + kb * 16 + lhi * 8) ^ ((row & 7) << 3);
    af[kb] = *(const bf16x8*)(&lA[so]);
  }
  f32x16 acc0 = {}, acc1 = {}, acc2 = {}, acc3 = {};
#pragma unroll
  for (int kb = 0; kb < 8; ++kb) {
    int ko = kb * 16 + lhi * 8;
    int sw = (lp & 7) << 3;
    bf16x8 b0 = *(const bf16x8*)(&lw1t[((lp + 0) * 128 + ko) ^ sw]);
    bf16x8 b1 = *(const bf16x8*)(&lw1t[((lp + 32) * 128 + ko) ^ sw]);
    bf16x8 b2 = *(const bf16x8*)(&lw1t[((lp + 64) * 128 + ko) ^ sw]);
    bf16x8 b3 = *(const bf16x8*)(&lw1t[((lp + 96) * 128 + ko) ^ sw]);
    acc0 = __builtin_amdgcn_mfma_f32_32x32x16_bf16(af[kb], b0, acc0, 0, 0, 0);
    acc1 = __builtin_amdgcn_mfma_f32_32x32x16_bf16(af[kb], b1, acc1, 0, 0, 0);
    acc2 = __builtin_amdgcn_mfma_f32_32x32x16_bf16(af[kb], b2, acc2, 0, 0, 0);
    acc3 = __builtin_amdgcn_mfma_f32_32x32x16_bf16(af[kb], b3, acc3, 0, 0, 0);
  }

#pragma unroll
  for (int r = 0; r < 16; ++r) {
    int row_local = wbase + (r & 3) + 8 * (r >> 2) + 4 * lhi;
    float dv = ldv[row_local];
    int rowg = rowbase + row_local;
    bool ok = (rowg < n) && !(l & 1);
    size_t base = (size_t)rowg * 64 + (lp >> 1);
    {
      float v = acc0[r] * dv; float o = __shfl_xor(v, 1, 64);
      if (ok) H1n[base + 0] = bf16rtn(v) | (bf16rtn(o) << 16);
    }
    {
      float v = acc1[r] * dv; float o = __shfl_xor(v, 1, 64);
      if (ok) H1n[base + 16] = bf16rtn(v) | (bf16rtn(o) << 16);
    }
    {
      float v = acc2[r] * dv; float o = __shfl_xor(v, 1, 64);
      if (ok) H1n[base + 32] = bf16rtn(v) | (bf16rtn(o) << 16);
    }
    {
      float v = acc3[r] * dv; float o = __shfl_xor(v, 1, 64);
      if (ok) H1n[base + 48] = bf16rtn(v) | (bf16rtn(o) << 16);
    }
  }
}

// ---------- agg1 (wave per node, R8 form): sum bf16 rows, relu, @Wf ----------
__global__ __launch_bounds__(256) void agg1_kernel(
    const unsigned* __restrict__ H1n, const int* __restrict__ csr,
    const int* __restrict__ offsets, const int* __restrict__ counts,
    const float* __restrict__ dinv, const float* __restrict__ b1,
    const float* __restrict__ Wf, float* __restrict__ Zn, int n) {
  int lane = threadIdx.x & 63;
  int node = blockIdx.x * 4 + (threadIdx.x >> 6);
  if (node >= n) return;
  int c0 = lane * 2;

  float di = dinv[node];
  float2 acc = bf2unpack(H1n[(size_t)node * 64 + lane]);  // self-loop term

  int off = __builtin_amdgcn_readfirstlane(offsets[node]);
  int cnt = __builtin_amdgcn_readfirstlane(counts[node]);
  int e = 0;
  for (; e + 16 <= cnt; e += 16) {
    int s[16];
#pragma unroll
    for (int j = 0; j < 16; ++j) s[j] = __builtin_amdgcn_readfirstlane(csr[off + e + j]);
    unsigned u[16];
#pragma unroll
    for (int j = 0; j < 16; ++j) u[j] = H1n[(size_t)s[j] * 64 + lane];
#pragma unroll
    for (int j = 0; j < 16; ++j) {
      float2 h = bf2unpack(u[j]);
      acc.x += h.x;
      acc.y += h.y;
    }
  }
  for (; e + 4 <= cnt; e += 4) {
    int s[4];
#pragma unroll
    for (int j = 0; j < 4; ++j) s[j] = __builtin_amdgcn_readfirstlane(csr[off + e + j]);
    unsigned u[4];
#pragma unroll
    for (int j = 0; j < 4; ++j) u[j] = H1n[(size_t)s[j] * 64 + lane];
#pragma unroll
    for (int j = 0; j < 4; ++j) {
      float2 h = bf2unpack(u[j]);
      acc.x += h.x;
      acc.y += h.y;
    }
  }
  for (; e < cnt; ++e) {
    int s0 = __builtin_amdgcn_readfirstlane(csr[off + e]);
    float2 h0 = bf2unpack(H1n[(size_t)s0 * 64 + lane]);
    acc.x += h0.x;
    acc.y += h0.y;
  }

  float2 bb = *(const float2*)(b1 + c0);
  float v0 = fmaf(acc.x, di, bb.x); v0 = v0 > 0.f ? v0 : 0.f;
  float v1 = fmaf(acc.y, di, bb.y); v1 = v1 > 0.f ? v1 : 0.f;

  float4 wv = *(const float4*)(Wf + c0 * 2);
  float z0 = v0 * wv.x + v1 * wv.z;
  float z1 = v0 * wv.y + v1 * wv.w;
#pragma unroll
  for (int m = 32; m > 0; m >>= 1) {
    z0 += __shfl_xor(z0, m, 64);
    z1 += __shfl_xor(z1, m, 64);
  }
  if (lane == 0) {
    Zn[(size_t)node * 2 + 0] = z0 * di;
    Zn[(size_t)node * 2 + 1] = z1 * di;
  }
}

// ---------- agg2 (thread per node): out = di*(Zn[i] + sum Zn[s]) + bf ----------
__global__ void agg2_kernel(const float* __restrict__ Znb, const int* __restrict__ csr,
                            const int* __restrict__ offsets, const int* __restrict__ counts,
                            const float* __restrict__ dinv, const float* __restrict__ bf,
                            float* __restrict__ out, int n) {
  int i = blockIdx.x * blockDim.x + threadIdx.x;
  if (i >= n) return;
  float di = dinv[i];
  float2 z = *(const float2*)(Znb + (size_t)i * 2);
  float ax = z.x, ay = z.y;   // self-loop term
  int off = offsets[i], cnt = counts[i];
  int e = 0;
  for (; e + 4 <= cnt; e += 4) {
    int s0 = csr[off + e + 0], s1 = csr[off + e + 1];
    int s2 = csr[off + e + 2], s3 = csr[off + e + 3];
    float2 z0 = *(const float2*)(Znb + (size_t)s0 * 2);
    float2 z1 = *(const float2*)(Znb + (size_t)s1 * 2);
    float2 z2 = *(const float2*)(Znb + (size_t)s2 * 2);
    float2 z3 = *(const float2*)(Znb + (size_t)s3 * 2);
    ax += (z0.x + z1.x) + (z2.x + z3.x);
    ay += (z0.y + z1.y) + (z2.y + z3.y);
  }
  for (; e < cnt; ++e) {
    int s = csr[off + e];
    float2 zs = *(const float2*)(Znb + (size_t)s * 2);
    ax += zs.x;
    ay += zs.y;
  }
  out[(size_t)i * 2 + 0] = fmaf(ax, di, bf[0]);
  out[(size_t)i * 2 + 1] = fmaf(ay, di, bf[1]);
}

extern "C" void kernel_launch(void* const* d_in, const int* in_sizes, int n_in,
                              void* d_out, int out_size, void* d_ws, size_t ws_size,
                              hipStream_t stream) {
  const float* x = (const float*)d_in[0];
  const int* ei = (const int*)d_in[1];
  const float* fmask = (const float*)d_in[2];
  const float* W1 = (const float*)d_in[3];
  const float* b1 = (const float*)d_in[4];
  const float* W2 = (const float*)d_in[5];
  const float* b2 = (const float*)d_in[6];
  const float* Wc = (const float*)d_in[7];
  const float* bc = (const float*)d_in[8];

  int N = in_sizes[0] / 128;
  int E = in_sizes[1] / 2;
  const int* src = ei;
  const int* dst = ei + E;

  char* base = (char*)d_ws;
  size_t o = 0;
  auto take = [&](size_t bytes) -> char* {
    char* p = base + o;
    o = (o + bytes + 255) & ~(size_t)255;
    return p;
  };
  int* counts = (int*)take((size_t)N * 4);
  int* offsets = (int*)take((size_t)N * 4);
  float* dinv = (float*)take((size_t)N * 4);
  int* csr = (int*)take((size_t)NBIN * CAPB * 4);       // padded per-bin regions
  unsigned* H1n = (unsigned*)take((size_t)N * 64 * 4);  // packed bf16 rows
  float* Zn = (float*)take((size_t)N * 2 * 4);
  float* sm = (float*)take(128 * 4);
  float* Wf = (float*)take(256 * 4);
  float* bf = (float*)take(2 * 4);
  unsigned* W1Tg = (unsigned*)take(8192 * 4);           // W1^T bf16 packed
  int* cursor = (int*)take((size_t)NBIN * 8 * 4);       // per-(bin,sub) cursors
  unsigned* psd = (unsigned*)take((size_t)NBIN * CAPB * 4);  // padded (src|ld<<20)
  (void)ws_size;
  (void)n_in;
  (void)out_size;

  // bin(d) = umulhi(d*NBIN, multN) ~ floor(d*NBIN/N); multN = ceil(2^32/N)
  unsigned multN = (unsigned)(((1ull << 32) + N - 1) / (unsigned long long)N);

  prep_kernel<<<34, 256, 0, stream>>>(fmask, W2, b2, Wc, bc, W1, sm, Wf, bf, W1Tg, cursor);
  partP_kernel<<<PNB, 256, 0, stream>>>(src, dst, cursor, psd, E, multN);
  csrbuild_kernel<<<NBIN, 256, 0, stream>>>(psd, cursor, offsets, counts, dinv, csr,
                                            N, multN);
  gemm1_mfma_kernel<<<(N + 127) / 128, 256, 0, stream>>>(x, W1Tg, sm, dinv, H1n, N);
  agg1_kernel<<<(N + 3) / 4, 256, 0, stream>>>(H1n, csr, offsets, counts, dinv, b1, Wf, Zn, N);
  agg2_kernel<<<(N + 255) / 256, 256, 0, stream>>>(Zn, csr, offsets, counts, dinv, bf,
                                                   (float*)d_out, N);
}

// Round 12
// 171.373 us; speedup vs baseline: 2.0034x; 2.0034x over previous
//
#include <hip/hip_runtime.h>
#include <math.h>

// ---------------------------------------------------------------------------
// GCN fraud-model forward:
//   out = A(relu(A(x*sig(mask) @ W1) + b1) @ (W2@Wc)) + (b2@Wc + bc)
// A-linearity folds W2@Wc -> [128,2].
//
// R3: dinv folded into stored rows; H1n packed bf16 (256B/row).
// R4: gemm1 -> MFMA bf16 32x32x16, XOR-swizzled LDS.
// R6: line-local CSR build (bin partition + per-bin block).
// R8: packed edges (src|ld<<20), scalarized agg index streams. [171us BEST]
// R9: coop grid.sync REGRESSED 2.6x (cross-XCD L2 drains at each barrier).
// R10: agg1 2-nodes/wave REGRESSED (59.6->71.6us: halved TLP > added ILP).
// R11: scan-free partition REGRESSED 2x (per-edge GLOBAL atomic = ~900cyc
//      latency-serialized, VALUBusy 0.4%). hist+scan IS the fast path: it
//      reserves private per-(bin,block) runs so scatter cursors live in LDS.
// R12: exact revert to R8. agg1 is at the random-gather floor (26 cyc/edge
//      = 10B/cyc/CU, m13); FETCH pinned at 190MB across 4 attempts.
// ---------------------------------------------------------------------------

constexpr int NBIN = 256;  // partition bins (~391 nodes, ~6250 edges each)
constexpr int PNB = 128;   // histogram/scatter blocks

typedef __attribute__((ext_vector_type(8))) short bf16x8;
typedef __attribute__((ext_vector_type(16))) float f32x16;

__device__ __forceinline__ unsigned bf16rtn(float f) {
  unsigned b = __float_as_uint(f);
  b += 0x7FFFu + ((b >> 16) & 1u);   // round-to-nearest-even
  return b >> 16;
}
__device__ __forceinline__ float2 bf2unpack(unsigned u) {
  float2 r;
  r.x = __uint_as_float(u << 16);
  r.y = __uint_as_float(u & 0xFFFF0000u);
  return r;
}

// ---------- fused: hist (blocks 0..PNB-1) + prep (PNB) + w1t (PNB+1..) ------
__global__ void histP_prep_kernel(const int* __restrict__ dst, int* __restrict__ hist,
                                  int E, unsigned multN,
                                  const float* __restrict__ fmask, const float* __restrict__ W2,
                                  const float* __restrict__ b2, const float* __restrict__ Wc,
                                  const float* __restrict__ bc, const float* __restrict__ W1,
                                  float* __restrict__ sm, float* __restrict__ Wf,
                                  float* __restrict__ bf, unsigned* __restrict__ W1Tg) {
  int t = threadIdx.x;
  if (blockIdx.x >= PNB) {
    int bb = blockIdx.x - PNB;
    if (bb == 0) {
      if (t < 128) {
        sm[t] = 1.0f / (1.0f + expf(-fmask[t]));
        float w0 = 0.f, w1 = 0.f;
        for (int k = 0; k < 128; ++k) {
          float v = W2[t * 128 + k];
          w0 = fmaf(v, Wc[k * 2 + 0], w0);
          w1 = fmaf(v, Wc[k * 2 + 1], w1);
        }
        Wf[t * 2 + 0] = w0;
        Wf[t * 2 + 1] = w1;
      }
      if (t >= 128 && t < 130) {
        int j = t - 128;
        float s = bc[j];
        for (int k = 0; k < 128; ++k) s = fmaf(b2[k], Wc[k * 2 + j], s);
        bf[j] = s;
      }
    } else {
      int p = (bb - 1) * 256 + t;  // 0..8191
      if (p < 8192) {
        int j = p >> 6;
        int kp = (p & 63) * 2;
        float a = W1[(size_t)kp * 128 + j];
        float b = W1[(size_t)(kp + 1) * 128 + j];
        W1Tg[p] = bf16rtn(a) | (bf16rtn(b) << 16);
      }
    }
    return;
  }
  __shared__ int h[NBIN];
  for (int i = t; i < NBIN; i += blockDim.x) h[i] = 0;
  __syncthreads();
  int per = (E + PNB - 1) / PNB;
  int e0 = blockIdx.x * per, e1 = min(E, e0 + per);
  for (int e = e0 + t; e < e1; e += blockDim.x) {
    int b = __umulhi((unsigned)dst[e] * NBIN, multN);
    atomicAdd(&h[b], 1);
  }
  __syncthreads();
  for (int i = t; i < NBIN; i += blockDim.x) hist[i * PNB + blockIdx.x] = h[i];
}

// ---------- partition pass 2: exclusive scan of hist[NBIN*PNB] ----------
__global__ void scanP_kernel(int* __restrict__ hist, int* __restrict__ binstart, int E) {
  __shared__ int sh[256];
  int t = threadIdx.x;
  const int PER = (NBIN * PNB) / 256;  // 128
  int base = t * PER;
  int s = 0;
  for (int j = 0; j < PER; ++j) s += hist[base + j];
  sh[t] = s;
  __syncthreads();
  for (int off = 1; off < 256; off <<= 1) {
    int add = (t >= off) ? sh[t - off] : 0;
    __syncthreads();
    sh[t] += add;
    __syncthreads();
  }
  int run = sh[t] - s;  // exclusive
  for (int j = 0; j < PER; ++j) {
    int v = hist[base + j];
    hist[base + j] = run;
    int idx = base + j;
    if ((idx & (PNB - 1)) == 0) binstart[idx / PNB] = run;
    run += v;
  }
  if (t == 0) binstart[NBIN] = E;
}

// ---------- partition pass 3: scatter packed (src | local_d<<20) ----------
__global__ void partP_kernel(const int* __restrict__ src, const int* __restrict__ dst,
                             const int* __restrict__ hist, unsigned* __restrict__ psd,
                             int E, unsigned multN) {
  __shared__ int cur[NBIN];
  __shared__ int llo[NBIN];
  int t = threadIdx.x;
  unsigned long long denom = (unsigned long long)multN * NBIN;
  for (int i = t; i < NBIN; i += blockDim.x) {
    cur[i] = hist[i * PNB + blockIdx.x];
    llo[i] = (int)((((unsigned long long)i << 32) + denom - 1) / denom);
  }
  __syncthreads();
  int per = (E + PNB - 1) / PNB;
  int e0 = blockIdx.x * per, e1 = min(E, e0 + per);
  for (int e = e0 + t; e < e1; e += blockDim.x) {
    int d = dst[e];
    int s = src[e];
    int b = __umulhi((unsigned)d * NBIN, multN);
    int p = atomicAdd(&cur[b], 1);
    psd[p] = (unsigned)s | ((unsigned)(d - llo[b]) << 20);
  }
}

// ---------- per-bin CSR build from packed edges ----------
__global__ __launch_bounds__(256) void csrbuild_kernel(
    const unsigned* __restrict__ psd, const int* __restrict__ binstart,
    int* __restrict__ offsets, int* __restrict__ counts, float* __restrict__ dinv,
    int* __restrict__ csr, int n, unsigned multN) {
  __shared__ int ldeg[512];
  __shared__ int lcur[512];
  __shared__ int sh[256];
  int b = blockIdx.x, t = threadIdx.x;
  unsigned long long denom = (unsigned long long)multN * NBIN;
  int lo = (int)((((unsigned long long)b << 32) + denom - 1) / denom);
  int hi = (int)((((unsigned long long)(b + 1) << 32) + denom - 1) / denom);
  if (hi > n) hi = n;
  if (lo > n) lo = n;
  int s0 = binstart[b], s1 = binstart[b + 1];
#pragma unroll
  for (int j = 0; j < 2; ++j) ldeg[t * 2 + j] = 0;
  __syncthreads();
  for (int e = s0 + t; e < s1; e += 256) atomicAdd(&ldeg[psd[e] >> 20], 1);
  __syncthreads();
  int c[2], loc = 0;
#pragma unroll
  for (int j = 0; j < 2; ++j) {
    c[j] = ldeg[t * 2 + j];
    loc += c[j];
  }
  sh[t] = loc;
  __syncthreads();
  for (int off = 1; off < 256; off <<= 1) {
    int add = (t >= off) ? sh[t - off] : 0;
    __syncthreads();
    sh[t] += add;
    __syncthreads();
  }
  int run = sh[t] - loc;  // exclusive
#pragma unroll
  for (int j = 0; j < 2; ++j) {
    int idx = t * 2 + j;
    lcur[idx] = run;
    int node = lo + idx;
    if (node < hi) {
      offsets[node] = s0 + run;
      counts[node] = c[j];
      dinv[node] = rsqrtf((float)(c[j] + 1));
    }
    run += c[j];
  }
  __syncthreads();
  for (int e = s0 + t; e < s1; e += 256) {
    unsigned pd = psd[e];
    int p = atomicAdd(&lcur[pd >> 20], 1);
    csr[s0 + p] = (int)(pd & 0xFFFFFu);
  }
}

// ---------- GEMM1 (MFMA): H1n = dinv[row] * ((x*sm) @ W1) in packed bf16 ----
__global__ __launch_bounds__(256) void gemm1_mfma_kernel(
    const float* __restrict__ x, const unsigned* __restrict__ W1Tg,
    const float* __restrict__ sm, const float* __restrict__ dinv,
    unsigned* __restrict__ H1n, int n) {
  __shared__ short lw1t[16384];  // 32 KB, W1T[j][k] bf16, swizzled
  __shared__ short lA[16384];    // 32 KB, A[r][k] bf16, swizzled
  __shared__ float ldv[128];
  int t = threadIdx.x;
  int rowbase = blockIdx.x * 128;

  if (t < 128) {
    int rg = rowbase + t;
    ldv[t] = (rg < n) ? dinv[rg] : 0.f;
  }
#pragma unroll
  for (int i = 0; i < 8; ++i) {
    int g = t + i * 256;
    int j = g >> 4;
    int c8 = (g & 15) * 8;
    uint4 v = *(const uint4*)(W1Tg + j * 64 + (c8 >> 1));
    int so = (j * 128 + c8) ^ ((j & 7) << 3);
    *(uint4*)(&lw1t[so]) = v;
  }
#pragma unroll
  for (int i = 0; i < 8; ++i) {
    int g = t + i * 256;
    int r = g >> 4;
    int c8 = (g & 15) * 8;
    int rowg = rowbase + r;
    uint4 p = {0, 0, 0, 0};
    if (rowg < n) {
      const float* xp = x + (size_t)rowg * 128 + c8;
      float4 xa = *(const float4*)(xp);
      float4 xb = *(const float4*)(xp + 4);
      float4 sa = *(const float4*)(sm + c8);
      float4 sb = *(const float4*)(sm + c8 + 4);
      p.x = bf16rtn(xa.x * sa.x) | (bf16rtn(xa.y * sa.y) << 16);
      p.y = bf16rtn(xa.z * sa.z) | (bf16rtn(xa.w * sa.w) << 16);
      p.z = bf16rtn(xb.x * sb.x) | (bf16rtn(xb.y * sb.y) << 16);
      p.w = bf16rtn(xb.z * sb.z) | (bf16rtn(xb.w * sb.w) << 16);
    }
    int so = (r * 128 + c8) ^ ((r & 7) << 3);
    *(uint4*)(&lA[so]) = p;
  }
  __syncthreads();

  int l = t & 63;
  int w = t >> 6;
  int wbase = w * 32;
  int lp = l & 31;
  int lhi = l >> 5;

  bf16x8 af[8];
#pragma unroll
  for (int kb = 0; kb < 8; ++kb) {
    int row = wbase + lp;
    int so = (row * 128 + kb * 16 + lhi * 8) ^ ((row & 7) << 3);
    af[kb] = *(const bf16x8*)(&lA[so]);
  }
  f32x16 acc0 = {}, acc1 = {}, acc2 = {}, acc3 = {};
#pragma unroll
  for (int kb = 0; kb < 8; ++kb) {
    int ko = kb * 16 + lhi * 8;
    int sw = (lp & 7) << 3;
    bf16x8 b0 = *(const bf16x8*)(&lw1t[((lp + 0) * 128 + ko) ^ sw]);
    bf16x8 b1 = *(const bf16x8*)(&lw1t[((lp + 32) * 128 + ko) ^ sw]);
    bf16x8 b2 = *(const bf16x8*)(&lw1t[((lp + 64) * 128 + ko) ^ sw]);
    bf16x8 b3 = *(const bf16x8*)(&lw1t[((lp + 96) * 128 + ko) ^ sw]);
    acc0 = __builtin_amdgcn_mfma_f32_32x32x16_bf16(af[kb], b0, acc0, 0, 0, 0);
    acc1 = __builtin_amdgcn_mfma_f32_32x32x16_bf16(af[kb], b1, acc1, 0, 0, 0);
    acc2 = __builtin_amdgcn_mfma_f32_32x32x16_bf16(af[kb], b2, acc2, 0, 0, 0);
    acc3 = __builtin_amdgcn_mfma_f32_32x32x16_bf16(af[kb], b3, acc3, 0, 0, 0);
  }

#pragma unroll
  for (int r = 0; r < 16; ++r) {
    int row_local = wbase + (r & 3) + 8 * (r >> 2) + 4 * lhi;
    float dv = ldv[row_local];
    int rowg = rowbase + row_local;
    bool ok = (rowg < n) && !(l & 1);
    size_t base = (size_t)rowg * 64 + (lp >> 1);
    {
      float v = acc0[r] * dv; float o = __shfl_xor(v, 1, 64);
      if (ok) H1n[base + 0] = bf16rtn(v) | (bf16rtn(o) << 16);
    }
    {
      float v = acc1[r] * dv; float o = __shfl_xor(v, 1, 64);
      if (ok) H1n[base + 16] = bf16rtn(v) | (bf16rtn(o) << 16);
    }
    {
      float v = acc2[r] * dv; float o = __shfl_xor(v, 1, 64);
      if (ok) H1n[base + 32] = bf16rtn(v) | (bf16rtn(o) << 16);
    }
    {
      float v = acc3[r] * dv; float o = __shfl_xor(v, 1, 64);
      if (ok) H1n[base + 48] = bf16rtn(v) | (bf16rtn(o) << 16);
    }
  }
}

// ---------- agg1 (wave per node): sum bf16 rows, h1 = relu(di*acc+b1),
//            Zn = di * (h1 @ Wf). Index stream scalarized. ----------
__global__ __launch_bounds__(256) void agg1_kernel(
    const unsigned* __restrict__ H1n, const int* __restrict__ csr,
    const int* __restrict__ offsets, const int* __restrict__ counts,
    const float* __restrict__ dinv, const float* __restrict__ b1,
    const float* __restrict__ Wf, float* __restrict__ Zn, int n) {
  int lane = threadIdx.x & 63;
  int node = blockIdx.x * 4 + (threadIdx.x >> 6);
  if (node >= n) return;
  int c0 = lane * 2;

  float di = dinv[node];
  float2 acc = bf2unpack(H1n[(size_t)node * 64 + lane]);  // self-loop term

  int off = __builtin_amdgcn_readfirstlane(offsets[node]);
  int cnt = __builtin_amdgcn_readfirstlane(counts[node]);
  int e = 0;
  for (; e + 16 <= cnt; e += 16) {
    int s[16];
#pragma unroll
    for (int j = 0; j < 16; ++j) s[j] = __builtin_amdgcn_readfirstlane(csr[off + e + j]);
    unsigned u[16];
#pragma unroll
    for (int j = 0; j < 16; ++j) u[j] = H1n[(size_t)s[j] * 64 + lane];
#pragma unroll
    for (int j = 0; j < 16; ++j) {
      float2 h = bf2unpack(u[j]);
      acc.x += h.x;
      acc.y += h.y;
    }
  }
  for (; e + 4 <= cnt; e += 4) {
    int s[4];
#pragma unroll
    for (int j = 0; j < 4; ++j) s[j] = __builtin_amdgcn_readfirstlane(csr[off + e + j]);
    unsigned u[4];
#pragma unroll
    for (int j = 0; j < 4; ++j) u[j] = H1n[(size_t)s[j] * 64 + lane];
#pragma unroll
    for (int j = 0; j < 4; ++j) {
      float2 h = bf2unpack(u[j]);
      acc.x += h.x;
      acc.y += h.y;
    }
  }
  for (; e < cnt; ++e) {
    int s0 = __builtin_amdgcn_readfirstlane(csr[off + e]);
    float2 h0 = bf2unpack(H1n[(size_t)s0 * 64 + lane]);
    acc.x += h0.x;
    acc.y += h0.y;
  }

  float2 bb = *(const float2*)(b1 + c0);
  float v0 = fmaf(acc.x, di, bb.x); v0 = v0 > 0.f ? v0 : 0.f;
  float v1 = fmaf(acc.y, di, bb.y); v1 = v1 > 0.f ? v1 : 0.f;

  float4 wv = *(const float4*)(Wf + c0 * 2);
  float z0 = v0 * wv.x + v1 * wv.z;
  float z1 = v0 * wv.y + v1 * wv.w;
#pragma unroll
  for (int m = 32; m > 0; m >>= 1) {
    z0 += __shfl_xor(z0, m, 64);
    z1 += __shfl_xor(z1, m, 64);
  }
  if (lane == 0) {
    Zn[(size_t)node * 2 + 0] = z0 * di;
    Zn[(size_t)node * 2 + 1] = z1 * di;
  }
}

// ---------- agg2 (thread per node): out = di*(Zn[i] + sum Zn[s]) + bf ----------
__global__ void agg2_kernel(const float* __restrict__ Znb, const int* __restrict__ csr,
                            const int* __restrict__ offsets, const int* __restrict__ counts,
                            const float* __restrict__ dinv, const float* __restrict__ bf,
                            float* __restrict__ out, int n) {
  int i = blockIdx.x * blockDim.x + threadIdx.x;
  if (i >= n) return;
  float di = dinv[i];
  float2 z = *(const float2*)(Znb + (size_t)i * 2);
  float ax = z.x, ay = z.y;   // self-loop term
  int off = offsets[i], cnt = counts[i];
  int e = 0;
  for (; e + 4 <= cnt; e += 4) {
    int s0 = csr[off + e + 0], s1 = csr[off + e + 1];
    int s2 = csr[off + e + 2], s3 = csr[off + e + 3];
    float2 z0 = *(const float2*)(Znb + (size_t)s0 * 2);
    float2 z1 = *(const float2*)(Znb + (size_t)s1 * 2);
    float2 z2 = *(const float2*)(Znb + (size_t)s2 * 2);
    float2 z3 = *(const float2*)(Znb + (size_t)s3 * 2);
    ax += (z0.x + z1.x) + (z2.x + z3.x);
    ay += (z0.y + z1.y) + (z2.y + z3.y);
  }
  for (; e < cnt; ++e) {
    int s = csr[off + e];
    float2 zs = *(const float2*)(Znb + (size_t)s * 2);
    ax += zs.x;
    ay += zs.y;
  }
  out[(size_t)i * 2 + 0] = fmaf(ax, di, bf[0]);
  out[(size_t)i * 2 + 1] = fmaf(ay, di, bf[1]);
}

extern "C" void kernel_launch(void* const* d_in, const int* in_sizes, int n_in,
                              void* d_out, int out_size, void* d_ws, size_t ws_size,
                              hipStream_t stream) {
  const float* x = (const float*)d_in[0];
  const int* ei = (const int*)d_in[1];
  const float* fmask = (const float*)d_in[2];
  const float* W1 = (const float*)d_in[3];
  const float* b1 = (const float*)d_in[4];
  const float* W2 = (const float*)d_in[5];
  const float* b2 = (const float*)d_in[6];
  const float* Wc = (const float*)d_in[7];
  const float* bc = (const float*)d_in[8];

  int N = in_sizes[0] / 128;
  int E = in_sizes[1] / 2;
  const int* src = ei;
  const int* dst = ei + E;

  char* base = (char*)d_ws;
  size_t o = 0;
  auto take = [&](size_t bytes) -> char* {
    char* p = base + o;
    o = (o + bytes + 255) & ~(size_t)255;
    return p;
  };
  int* counts = (int*)take((size_t)N * 4);
  int* offsets = (int*)take((size_t)N * 4);
  float* dinv = (float*)take((size_t)N * 4);
  int* csr = (int*)take((size_t)E * 4);
  unsigned* H1n = (unsigned*)take((size_t)N * 64 * 4);  // packed bf16 rows
  float* Zn = (float*)take((size_t)N * 2 * 4);
  float* sm = (float*)take(128 * 4);
  float* Wf = (float*)take(256 * 4);
  float* bf = (float*)take(2 * 4);
  unsigned* W1Tg = (unsigned*)take(8192 * 4);           // W1^T bf16 packed
  int* hist = (int*)take((size_t)NBIN * PNB * 4);       // partition histogram
  int* binstart = (int*)take((NBIN + 1) * 4);
  unsigned* psd = (unsigned*)take((size_t)E * 4);       // packed (src|ld<<20)
  (void)ws_size;
  (void)n_in;
  (void)out_size;

  // bin(d) = umulhi(d*NBIN, multN) ~ floor(d*NBIN/N); multN = ceil(2^32/N)
  unsigned multN = (unsigned)(((1ull << 32) + N - 1) / (unsigned long long)N);

  histP_prep_kernel<<<PNB + 33, 256, 0, stream>>>(dst, hist, E, multN, fmask, W2, b2,
                                                  Wc, bc, W1, sm, Wf, bf, W1Tg);
  scanP_kernel<<<1, 256, 0, stream>>>(hist, binstart, E);
  partP_kernel<<<PNB, 256, 0, stream>>>(src, dst, hist, psd, E, multN);
  csrbuild_kernel<<<NBIN, 256, 0, stream>>>(psd, binstart, offsets, counts, dinv, csr,
                                            N, multN);
  gemm1_mfma_kernel<<<(N + 127) / 128, 256, 0, stream>>>(x, W1Tg, sm, dinv, H1n, N);
  agg1_kernel<<<(N + 3) / 4, 256, 0, stream>>>(H1n, csr, offsets, counts, dinv, b1, Wf, Zn, N);
  agg2_kernel<<<(N + 255) / 256, 256, 0, stream>>>(Zn, csr, offsets, counts, dinv, bf,
                                                   (float*)d_out, N);
}